// Round 13
// baseline (58.662 us; speedup 1.0000x reference)
//
#include <hip/hip_runtime.h>

namespace {

constexpr int H = 64, W = 64, N = H * W;
constexpr int BC = 24;        // B*C channels
constexpr float TINY = 1e-10f;
constexpr int BLOCK = 256;    // 4 waves, 1 per SIMD; 16 rows per lane
constexpr int PX = 16;        // rows per thread (wave band = 16 rows)
constexpr int PW = 64;        // halo plane stride (stride-1 lane access: free)
constexpr int PROWS = H + 6;  // 70: 3 zero rows each side (contraction r=3)
constexpr int NW = BLOCK / 64;

// 36 iterations, EMD snapshots after 12/24/36 (spacing 12), per-channel
// Aitken extrapolation (validated R10-R12; removes truncation error).

// gfx9 DPP whole-wave shifts; bound_ctrl=1 -> out-of-range lanes read 0,
// exactly matching the conv's zero padding (W == wave width == 64).
constexpr int DPP_WAVE_SHL1 = 0x130;
constexpr int DPP_WAVE_SHR1 = 0x138;

// taps g(d)=exp(-d^2); center exactly 1.0. Loop: radius 2 (tap absmax
// 0.0078 — verified R7/R8). Checkpoint contraction: radius 3.
constexpr float G1 = 0.36787944117144233f;
constexpr float G2 = 0.018315638888734179f;
constexpr float G3 = 1.2340980408667956e-4f;
// d^2 * g(d): center 0
constexpr float C1 = 0.36787944117144233f;
constexpr float C2 = 0.07326255555493671f;
constexpr float C3 = 1.110688236780116e-3f;

} // namespace

template <int CTRL>
__device__ __forceinline__ float dpp_shift(float v) {
  return __int_as_float(__builtin_amdgcn_update_dpp(
      0, __float_as_int(v), CTRL, 0xF, 0xF, true));
}

// explicit v_rcp_f32 + v_mul (1 ulp) — verified R12: __fdividef lowers to
// the full IEEE div sequence on ROCm; this was a 30% kernel-time cut.
__device__ __forceinline__ float fast_div(float n, float d) {
  return n * __builtin_amdgcn_rcpf(d);
}

__device__ __forceinline__ float block_reduce_sum(float v, float* red) {
#pragma unroll
  for (int off = 32; off; off >>= 1) v += __shfl_down(v, off, 64);
  const int wid = threadIdx.x >> 6;
  const int lane = threadIdx.x & 63;
  if (lane == 0) red[wid] = v;
  __syncthreads();
  if (threadIdx.x == 0) {
    float s = 0.f;
#pragma unroll
    for (int i = 0; i < NW; ++i) s += red[i];
    red[16] = s;
  }
  __syncthreads();
  return red[16];
}

__global__ __launch_bounds__(BLOCK, 1) void sinkhorn_kernel(
    const float* __restrict__ pred, const float* __restrict__ target,
    float* __restrict__ ws, unsigned* __restrict__ cnt,
    float* __restrict__ out) {
  __shared__ float PA[PROWS * PW];
  __shared__ float PB[PROWS * PW];
  __shared__ float red[17];

  const int tid = threadIdx.x;
  const int wid = tid >> 6;
  const int lane = tid & 63;
  const int bc = blockIdx.x;

  const int cx = lane;          // owned column
  const int cy0 = wid * PX;     // owned row band [cy0, cy0+16)

  const float* Pp = pred + bc * N;
  const float* Qp = target + bc * N;

  // ---- zero the permanent halo rows (0,1,2 and 67,68,69) of both planes ----
  for (int i = tid; i < 384; i += BLOCK) {
    int r = i >> 6, c = i & 63;
    int row = (r < 3) ? r : r + 64;   // rows 0,1,2,67,68,69
    PA[row * PW + c] = 0.f;
    PB[row * PW + c] = 0.f;
  }

  // ---- load + normalize (column layout) ----
  float ar[PX], br[PX], band[PX], eu[PX];
  float sa = 0.f, sb = 0.f;
#pragma unroll
  for (int k = 0; k < PX; ++k) {
    float va = Pp[(cy0 + k) * W + cx];
    float vb = Qp[(cy0 + k) * W + cx];
    ar[k] = va;
    br[k] = vb;
    sa += va;
    sb += vb;
  }
  sa = block_reduce_sum(sa, red);  // barriers also cover the halo-zero writes
  sb = block_reduce_sum(sb, red);
  const float isa = 1.0f / (sa + TINY);
  const float isb = 1.0f / (sb + TINY);
#pragma unroll
  for (int k = 0; k < PX; ++k) {
    ar[k] = ar[k] * isa + TINY;  // numerator of exp(u) = (a+TINY)/(S+TINY)
    br[k] = br[k] * isb + TINY;
    band[k] = 1.0f;              // EV = exp(v0) = 1
    eu[k] = 0.f;
  }

  // LDS addresses (hoisted). Plane row = logical row + 3.
  float* pa_w = &PA[(cy0 + 3) * PW + cx];
  float* pb_w = &PB[(cy0 + 3) * PW + cx];
  const float* pa_r = &PA[cy0 * PW + cx];
  const float* pb_r = &PB[cy0 * PW + cx];

  // radius-2 row conv along x via DPP wave shifts; stage-split so each
  // DPP stage is 16 independent ops (hides DPP write->read hazards).
  auto rowconv = [&](const float (&b)[PX], float (&R)[PX]) {
    float p1[PX], m1[PX], p2[PX], m2[PX];
#pragma unroll
    for (int k = 0; k < PX; ++k) {
      p1[k] = dpp_shift<DPP_WAVE_SHL1>(b[k]);
      m1[k] = dpp_shift<DPP_WAVE_SHR1>(b[k]);
    }
#pragma unroll
    for (int k = 0; k < PX; ++k) {
      p2[k] = dpp_shift<DPP_WAVE_SHL1>(p1[k]);
      m2[k] = dpp_shift<DPP_WAVE_SHR1>(m1[k]);
    }
#pragma unroll
    for (int k = 0; k < PX; ++k) {
      float s = fmaf(G1, m1[k] + p1[k], b[k]);  // center tap = 1.0
      R[k] = fmaf(G2, m2[k] + p2[k], s);
    }
  };

  // boundary rows for radius-2 neighbors: 0,1 and 14,15
  auto halo_write4 = [&](float* P, const float (&R)[PX]) {
    P[0 * PW] = R[0];
    P[1 * PW] = R[1];
    P[14 * PW] = R[14];
    P[15 * PW] = R[15];
  };

  // radius-2 col conv + divide, interior-first (k=2..13 need no halo, so
  // they execute while the 4 halo ds_reads are in flight).
  auto col_update = [&](const float* P, const float (&R)[PX],
                        const float (&num)[PX], float (&dst)[PX]) {
    float h0 = P[1 * PW];    // logical cy0-2
    float h1 = P[2 * PW];    // logical cy0-1
    float h2 = P[19 * PW];   // logical cy0+16
    float h3 = P[20 * PW];   // logical cy0+17
#pragma unroll
    for (int k = 2; k < 14; ++k) {
      float s = fmaf(G1, R[k - 1] + R[k + 1], R[k] + TINY);
      s = fmaf(G2, R[k - 2] + R[k + 2], s);
      dst[k] = fast_div(num[k], s);
    }
    {
      float s = fmaf(G1, h1 + R[1], R[0] + TINY);
      s = fmaf(G2, h0 + R[2], s);
      dst[0] = fast_div(num[0], s);
    }
    {
      float s = fmaf(G1, R[0] + R[2], R[1] + TINY);
      s = fmaf(G2, h1 + R[3], s);
      dst[1] = fast_div(num[1], s);
    }
    {
      float s = fmaf(G1, R[13] + R[15], R[14] + TINY);
      s = fmaf(G2, R[12] + h2, s);
      dst[14] = fast_div(num[14], s);
    }
    {
      float s = fmaf(G1, R[14] + h2, R[15] + TINY);
      s = fmaf(G2, R[13] + h3, s);
      dst[15] = fast_div(num[15], s);
    }
  };

  // one Sinkhorn half-step: dst = num / (K (*) src); 1 barrier
  auto half_iter = [&](float* Pw, const float* Pr, const float (&num)[PX],
                       const float (&src)[PX], float (&dst)[PX]) {
    float R[PX];
    rowconv(src, R);
    halo_write4(Pw, R);
    __syncthreads();
    col_update(Pr, R, num, dst);
  };

  // EMD contraction at a checkpoint (radius 3). Opening barrier: we write
  // BOTH planes, so wait for all waves' preceding col_update reads (the
  // steady loop is safe only because A/B phases touch disjoint planes).
  auto contraction = [&]() -> float {
    __syncthreads();
    float R1[PX], R2[PX];
    {
      float p1[PX], m1[PX], p2[PX], m2[PX], p3[PX], m3[PX];
#pragma unroll
      for (int k = 0; k < PX; ++k) {
        p1[k] = dpp_shift<DPP_WAVE_SHL1>(band[k]);
        m1[k] = dpp_shift<DPP_WAVE_SHR1>(band[k]);
      }
#pragma unroll
      for (int k = 0; k < PX; ++k) {
        p2[k] = dpp_shift<DPP_WAVE_SHL1>(p1[k]);
        m2[k] = dpp_shift<DPP_WAVE_SHR1>(m1[k]);
      }
#pragma unroll
      for (int k = 0; k < PX; ++k) {
        p3[k] = dpp_shift<DPP_WAVE_SHL1>(p2[k]);
        m3[k] = dpp_shift<DPP_WAVE_SHR1>(m2[k]);
      }
#pragma unroll
      for (int k = 0; k < PX; ++k) {
        float a1 = m1[k] + p1[k], a2 = m2[k] + p2[k], a3 = m3[k] + p3[k];
        float s1 = fmaf(G1, a1, band[k]);
        s1 = fmaf(G2, a2, s1);
        R1[k] = fmaf(G3, a3, s1);
        float s2 = C1 * a1;
        s2 = fmaf(C2, a2, s2);
        R2[k] = fmaf(C3, a3, s2);
      }
    }
    // boundary rows for radius-3 neighbors: 0,1,2 and 13,14,15
    pa_w[0 * PW] = R1[0];   pb_w[0 * PW] = R2[0];
    pa_w[1 * PW] = R1[1];   pb_w[1 * PW] = R2[1];
    pa_w[2 * PW] = R1[2];   pb_w[2 * PW] = R2[2];
    pa_w[13 * PW] = R1[13]; pb_w[13 * PW] = R2[13];
    pa_w[14 * PW] = R1[14]; pb_w[14 * PW] = R2[14];
    pa_w[15 * PW] = R1[15]; pb_w[15 * PW] = R2[15];
    __syncthreads();
    float local = 0.f;
    float w1[PX + 6], w2[PX + 6];
    w1[0] = pa_r[0 * PW];   w2[0] = pb_r[0 * PW];
    w1[1] = pa_r[1 * PW];   w2[1] = pb_r[1 * PW];
    w1[2] = pa_r[2 * PW];   w2[2] = pb_r[2 * PW];
#pragma unroll
    for (int k = 0; k < PX; ++k) {
      w1[3 + k] = R1[k];
      w2[3 + k] = R2[k];
    }
    w1[19] = pa_r[19 * PW]; w2[19] = pb_r[19 * PW];
    w1[20] = pa_r[20 * PW]; w2[20] = pb_r[20 * PW];
    w1[21] = pa_r[21 * PW]; w2[21] = pb_r[21 * PW];
#pragma unroll
    for (int k = 0; k < PX; ++k) {
      float s = C1 * (w1[k + 2] + w1[k + 4]);        // GC on G-plane (center 0)
      s = fmaf(C2, w1[k + 1] + w1[k + 5], s);
      s = fmaf(C3, w1[k + 0] + w1[k + 6], s);
      s += w2[k + 3];                                 // G on GC-plane, center 1
      s = fmaf(G1, w2[k + 2] + w2[k + 4], s);
      s = fmaf(G2, w2[k + 1] + w2[k + 5], s);
      s = fmaf(G3, w2[k + 0] + w2[k + 6], s);
      local = fmaf(eu[k], s, local);
    }
    return block_reduce_sum(local, red);  // internal barriers fence reads
  };

  // one checkpointed segment: LEN full iterations + 1 checkpoint iteration.
  auto run_seg = [&](auto len_c) -> float {
    constexpr int LEN = decltype(len_c)::value;
#pragma unroll
    for (int it = 0; it < LEN; ++it) {
      half_iter(pa_w, pa_r, ar, band, band);  // band := exp(u)
      half_iter(pb_w, pb_r, br, band, band);  // band := exp(v)
    }
    half_iter(pa_w, pa_r, ar, band, eu);      // checkpoint exp(u), kept
    half_iter(pb_w, pb_r, br, eu, band);      // checkpoint exp(v)
    return contraction();
  };

  // ---- 36 iterations, checkpoints after 12/24/36 ----
  float e0 = run_seg(std::integral_constant<int, 11>{});
  float e1 = run_seg(std::integral_constant<int, 11>{});
  float e2 = run_seg(std::integral_constant<int, 11>{});

  // ---- per-channel Aitken extrapolation + last-finisher mean ----
  if (tid == 0) {
    float d1 = e1 - e0, d2 = e2 - e1;
    float est = e2;
    float r = d2 / d1;                 // = q^12 (NaN/inf -> guards false)
    if (r > 0.001f && r < 0.97f) {
      float corr = d2 * r / (1.0f - r);
      corr = fminf(0.06f, fmaxf(-0.06f, corr));
      est = e2 + corr;
    }
    volatile float* wsv = ws;
    wsv[bc] = est;
    __threadfence();                   // publish before signaling
    unsigned old = atomicAdd(cnt, 1u); // device-scope
    if (old == BC - 1) {               // last finisher reduces
      __threadfence();
      float s = 0.f;
      for (int i = 0; i < BC; ++i) s += wsv[i];  // fixed order: deterministic
      out[0] = s * (1.0f / BC);
    }
  }
}

extern "C" void kernel_launch(void* const* d_in, const int* in_sizes, int n_in,
                              void* d_out, int out_size, void* d_ws,
                              size_t ws_size, hipStream_t stream) {
  const float* pred = (const float*)d_in[0];
  const float* target = (const float*)d_in[1];
  float* out = (float*)d_out;
  float* ws = (float*)d_ws;
  unsigned* cnt = (unsigned*)((char*)d_ws + 256);  // past ws[0..23]

  hipMemsetAsync(cnt, 0, 4, stream);  // stream-ordered, capture-safe
  sinkhorn_kernel<<<BC, BLOCK, 0, stream>>>(pred, target, ws, cnt, out);
}

// Round 15
// 44.235 us; speedup vs baseline: 1.3262x; 1.3262x over previous
//
#include <hip/hip_runtime.h>

namespace {

constexpr int H = 64, W = 64, N = H * W;
constexpr int BC = 24;        // B*C channels
constexpr float TINY = 1e-10f;
constexpr int BLOCK = 512;    // 8 waves, 2 per SIMD (R12-validated structure)
constexpr int PX = 8;         // rows per thread (wave band = 8 rows)
constexpr int PW = 64;        // halo plane stride (stride-1 lane access: free)
constexpr int PROWS = H + 6;  // 70: 3 zero rows each side (contraction r=3)
constexpr int NW = BLOCK / 64;

// 36 iterations, EMD snapshots after 12/24/36 (spacing 12), per-channel
// Aitken extrapolation (validated R10-R13; absmax 0.0156 at 36 iters).
// Reduction via a second kernel: cross-block communication through global
// memory within ONE kernel is NOT safe on MI355X (per-XCD L2 non-coherence
// bit us in R14); kernel boundaries guarantee visibility.

// gfx9 DPP whole-wave shifts; bound_ctrl=1 -> out-of-range lanes read 0,
// exactly matching the conv's zero padding (W == wave width == 64).
constexpr int DPP_WAVE_SHL1 = 0x130;
constexpr int DPP_WAVE_SHR1 = 0x138;

// taps g(d)=exp(-d^2); center exactly 1.0. Loop: radius 2 (tap absmax
// 0.0078 — verified R7/R8). Checkpoint contraction: radius 3.
constexpr float G1 = 0.36787944117144233f;
constexpr float G2 = 0.018315638888734179f;
constexpr float G3 = 1.2340980408667956e-4f;
// d^2 * g(d): center 0
constexpr float C1 = 0.36787944117144233f;
constexpr float C2 = 0.07326255555493671f;
constexpr float C3 = 1.110688236780116e-3f;

} // namespace

template <int CTRL>
__device__ __forceinline__ float dpp_shift(float v) {
  return __int_as_float(__builtin_amdgcn_update_dpp(
      0, __float_as_int(v), CTRL, 0xF, 0xF, true));
}

// explicit v_rcp_f32 + v_mul (1 ulp) — verified R12: __fdividef lowers to
// the full IEEE div sequence on ROCm; this was a 30% kernel-time cut.
__device__ __forceinline__ float fast_div(float n, float d) {
  return n * __builtin_amdgcn_rcpf(d);
}

__device__ __forceinline__ float block_reduce_sum(float v, float* red) {
#pragma unroll
  for (int off = 32; off; off >>= 1) v += __shfl_down(v, off, 64);
  const int wid = threadIdx.x >> 6;
  const int lane = threadIdx.x & 63;
  if (lane == 0) red[wid] = v;
  __syncthreads();
  if (threadIdx.x == 0) {
    float s = 0.f;
#pragma unroll
    for (int i = 0; i < NW; ++i) s += red[i];
    red[16] = s;
  }
  __syncthreads();
  return red[16];
}

__global__ __launch_bounds__(BLOCK, 2) void sinkhorn_kernel(
    const float* __restrict__ pred, const float* __restrict__ target,
    float* __restrict__ ws) {
  __shared__ float PA[PROWS * PW];
  __shared__ float PB[PROWS * PW];
  __shared__ float red[17];

  const int tid = threadIdx.x;
  const int wid = tid >> 6;
  const int lane = tid & 63;
  const int bc = blockIdx.x;

  const int cx = lane;          // owned column
  const int cy0 = wid * PX;     // owned row band [cy0, cy0+8)

  const float* Pp = pred + bc * N;
  const float* Qp = target + bc * N;

  // ---- zero the permanent halo rows (0,1,2 and 67,68,69) of both planes ----
  if (tid < 384) {
    int r = tid >> 6, c = tid & 63;
    int row = (r < 3) ? r : r + 64;
    PA[row * PW + c] = 0.f;
    PB[row * PW + c] = 0.f;
  }

  // ---- load + normalize (column layout) ----
  float ar[PX], br[PX], band[PX], eu[PX];
  float sa = 0.f, sb = 0.f;
#pragma unroll
  for (int k = 0; k < PX; ++k) {
    float va = Pp[(cy0 + k) * W + cx];
    float vb = Qp[(cy0 + k) * W + cx];
    ar[k] = va;
    br[k] = vb;
    sa += va;
    sb += vb;
  }
  sa = block_reduce_sum(sa, red);  // barriers also cover the halo-zero writes
  sb = block_reduce_sum(sb, red);
  const float isa = 1.0f / (sa + TINY);
  const float isb = 1.0f / (sb + TINY);
#pragma unroll
  for (int k = 0; k < PX; ++k) {
    ar[k] = ar[k] * isa + TINY;  // numerator of exp(u) = (a+TINY)/(S+TINY)
    br[k] = br[k] * isb + TINY;
    band[k] = 1.0f;              // EV = exp(v0) = 1
    eu[k] = 0.f;
  }

  // LDS addresses (hoisted). Plane row = logical row + 3.
  float* pa_w = &PA[(cy0 + 3) * PW + cx];
  float* pb_w = &PB[(cy0 + 3) * PW + cx];
  const float* pa_r = &PA[cy0 * PW + cx];
  const float* pb_r = &PB[cy0 * PW + cx];

  // radius-2 row conv of ONE row (along x, across lanes). R[k] depends only
  // on src[k], so boundary rows can be computed & written before interior.
  auto rowconv_k = [&](float bk) -> float {
    float p1 = dpp_shift<DPP_WAVE_SHL1>(bk);
    float m1 = dpp_shift<DPP_WAVE_SHR1>(bk);
    float p2 = dpp_shift<DPP_WAVE_SHL1>(p1);
    float m2 = dpp_shift<DPP_WAVE_SHR1>(m1);
    float s = fmaf(G1, m1 + p1, bk);  // center tap = 1.0
    return fmaf(G2, m2 + p2, s);
  };

  // radius-2 col conv + divide, interior-first (k=2..5 need no halo, so
  // they execute while the 4 halo ds_reads are in flight).
  auto col_update = [&](const float* P, const float (&R)[PX],
                        const float (&num)[PX], float (&dst)[PX]) {
    float h0 = P[1 * PW];    // logical cy0-2
    float h1 = P[2 * PW];    // logical cy0-1
    float h2 = P[11 * PW];   // logical cy0+8
    float h3 = P[12 * PW];   // logical cy0+9
#pragma unroll
    for (int k = 2; k < 6; ++k) {
      float s = fmaf(G1, R[k - 1] + R[k + 1], R[k] + TINY);
      s = fmaf(G2, R[k - 2] + R[k + 2], s);
      dst[k] = fast_div(num[k], s);
    }
    {
      float s = fmaf(G1, h1 + R[1], R[0] + TINY);
      s = fmaf(G2, h0 + R[2], s);
      dst[0] = fast_div(num[0], s);
    }
    {
      float s = fmaf(G1, R[0] + R[2], R[1] + TINY);
      s = fmaf(G2, h1 + R[3], s);
      dst[1] = fast_div(num[1], s);
    }
    {
      float s = fmaf(G1, R[5] + R[7], R[6] + TINY);
      s = fmaf(G2, R[4] + h2, s);
      dst[6] = fast_div(num[6], s);
    }
    {
      float s = fmaf(G1, R[6] + h2, R[7] + TINY);
      s = fmaf(G2, R[5] + h3, s);
      dst[7] = fast_div(num[7], s);
    }
  };

  // one Sinkhorn half-step: dst = num / (K (*) src); 1 barrier.
  // Boundary rows first + early ds_write -> write latency drains under
  // the interior rowconv, shrinking the pre-barrier lgkmcnt(0) wait.
  auto half_iter = [&](float* Pw, const float* Pr, const float (&num)[PX],
                       const float (&src)[PX], float (&dst)[PX]) {
    float R[PX];
    R[0] = rowconv_k(src[0]);
    R[1] = rowconv_k(src[1]);
    R[6] = rowconv_k(src[6]);
    R[7] = rowconv_k(src[7]);
    Pw[0 * PW] = R[0];
    Pw[1 * PW] = R[1];
    Pw[6 * PW] = R[6];
    Pw[7 * PW] = R[7];
    R[2] = rowconv_k(src[2]);
    R[3] = rowconv_k(src[3]);
    R[4] = rowconv_k(src[4]);
    R[5] = rowconv_k(src[5]);
    __syncthreads();
    col_update(Pr, R, num, dst);
  };

  // EMD contraction at a checkpoint (radius 3). Opening barrier: we write
  // BOTH planes, so wait for all waves' preceding col_update reads (the
  // steady loop is safe only because A/B phases touch disjoint planes).
  auto contraction = [&]() -> float {
    __syncthreads();
    float R1[PX], R2[PX];
    {
      float p1[PX], m1[PX], p2[PX], m2[PX], p3[PX], m3[PX];
#pragma unroll
      for (int k = 0; k < PX; ++k) {
        p1[k] = dpp_shift<DPP_WAVE_SHL1>(band[k]);
        m1[k] = dpp_shift<DPP_WAVE_SHR1>(band[k]);
      }
#pragma unroll
      for (int k = 0; k < PX; ++k) {
        p2[k] = dpp_shift<DPP_WAVE_SHL1>(p1[k]);
        m2[k] = dpp_shift<DPP_WAVE_SHR1>(m1[k]);
      }
#pragma unroll
      for (int k = 0; k < PX; ++k) {
        p3[k] = dpp_shift<DPP_WAVE_SHL1>(p2[k]);
        m3[k] = dpp_shift<DPP_WAVE_SHR1>(m2[k]);
      }
#pragma unroll
      for (int k = 0; k < PX; ++k) {
        float a1 = m1[k] + p1[k], a2 = m2[k] + p2[k], a3 = m3[k] + p3[k];
        float s1 = fmaf(G1, a1, band[k]);
        s1 = fmaf(G2, a2, s1);
        R1[k] = fmaf(G3, a3, s1);
        float s2 = C1 * a1;
        s2 = fmaf(C2, a2, s2);
        R2[k] = fmaf(C3, a3, s2);
      }
    }
    // boundary rows for radius-3 neighbors: 0,1,2 and 5,6,7
    pa_w[0 * PW] = R1[0];  pb_w[0 * PW] = R2[0];
    pa_w[1 * PW] = R1[1];  pb_w[1 * PW] = R2[1];
    pa_w[2 * PW] = R1[2];  pb_w[2 * PW] = R2[2];
    pa_w[5 * PW] = R1[5];  pb_w[5 * PW] = R2[5];
    pa_w[6 * PW] = R1[6];  pb_w[6 * PW] = R2[6];
    pa_w[7 * PW] = R1[7];  pb_w[7 * PW] = R2[7];
    __syncthreads();
    float local = 0.f;
    float w1[PX + 6], w2[PX + 6];
    w1[0] = pa_r[0 * PW];   w2[0] = pb_r[0 * PW];
    w1[1] = pa_r[1 * PW];   w2[1] = pb_r[1 * PW];
    w1[2] = pa_r[2 * PW];   w2[2] = pb_r[2 * PW];
#pragma unroll
    for (int k = 0; k < PX; ++k) {
      w1[3 + k] = R1[k];
      w2[3 + k] = R2[k];
    }
    w1[11] = pa_r[11 * PW]; w2[11] = pb_r[11 * PW];
    w1[12] = pa_r[12 * PW]; w2[12] = pb_r[12 * PW];
    w1[13] = pa_r[13 * PW]; w2[13] = pb_r[13 * PW];
#pragma unroll
    for (int k = 0; k < PX; ++k) {
      float s = C1 * (w1[k + 2] + w1[k + 4]);        // GC on G-plane (center 0)
      s = fmaf(C2, w1[k + 1] + w1[k + 5], s);
      s = fmaf(C3, w1[k + 0] + w1[k + 6], s);
      s += w2[k + 3];                                 // G on GC-plane, center 1
      s = fmaf(G1, w2[k + 2] + w2[k + 4], s);
      s = fmaf(G2, w2[k + 1] + w2[k + 5], s);
      s = fmaf(G3, w2[k + 0] + w2[k + 6], s);
      local = fmaf(eu[k], s, local);
    }
    return block_reduce_sum(local, red);  // internal barriers fence reads
  };

  // one checkpointed segment: LEN full iterations + 1 checkpoint iteration.
  // Compile-time LEN -> full unroll (R9/R12 evidence: unrolled is faster).
  auto run_seg = [&](auto len_c) -> float {
    constexpr int LEN = decltype(len_c)::value;
#pragma unroll
    for (int it = 0; it < LEN; ++it) {
      half_iter(pa_w, pa_r, ar, band, band);  // band := exp(u)
      half_iter(pb_w, pb_r, br, band, band);  // band := exp(v)
    }
    half_iter(pa_w, pa_r, ar, band, eu);      // checkpoint exp(u), kept
    half_iter(pb_w, pb_r, br, eu, band);      // checkpoint exp(v)
    return contraction();
  };

  // ---- 36 iterations, checkpoints after 12/24/36 ----
  float e0 = run_seg(std::integral_constant<int, 11>{});
  float e1 = run_seg(std::integral_constant<int, 11>{});
  float e2 = run_seg(std::integral_constant<int, 11>{});

  // ---- per-channel Aitken extrapolation; publish via kernel boundary ----
  if (tid == 0) {
    float d1 = e1 - e0, d2 = e2 - e1;
    float est = e2;
    float r = d2 / d1;                 // = q^12 (NaN/inf -> guards false)
    if (r > 0.001f && r < 0.97f) {
      float corr = d2 * r / (1.0f - r);
      corr = fminf(0.06f, fmaxf(-0.06f, corr));
      est = e2 + corr;
    }
    ws[bc] = est;
  }
}

__global__ void mean_kernel(const float* __restrict__ ws,
                            float* __restrict__ out) {
  int t = threadIdx.x;
  float v = (t < BC) ? ws[t] : 0.f;
#pragma unroll
  for (int off = 32; off; off >>= 1) v += __shfl_down(v, off, 64);
  if (t == 0) out[0] = v * (1.0f / BC);
}

extern "C" void kernel_launch(void* const* d_in, const int* in_sizes, int n_in,
                              void* d_out, int out_size, void* d_ws,
                              size_t ws_size, hipStream_t stream) {
  const float* pred = (const float*)d_in[0];
  const float* target = (const float*)d_in[1];
  float* out = (float*)d_out;
  float* ws = (float*)d_ws;

  sinkhorn_kernel<<<BC, BLOCK, 0, stream>>>(pred, target, ws);
  mean_kernel<<<1, 64, 0, stream>>>(ws, out);
}

// Round 16
// 39.863 us; speedup vs baseline: 1.4716x; 1.1097x over previous
//
#include <hip/hip_runtime.h>

namespace {

constexpr int H = 64, W = 64, N = H * W;
constexpr int BC = 24;        // B*C channels
constexpr float TINY = 1e-10f;
constexpr int BLOCK = 512;    // 8 waves, 2 per SIMD (R12/R15-validated)
constexpr int PX = 8;         // rows per thread (wave band = 8 rows)
constexpr int PW = 64;        // halo plane stride (stride-1 lane access: free)
constexpr int PROWS = H + 6;  // 70: 3 zero rows each side (contraction r=3)
constexpr int NW = BLOCK / 64;

// 32 iterations, EMD snapshots after 12/22/32 (spacing 10), per-channel
// Aitken extrapolation (scheme validated R10-R15). Reduction via a second
// kernel: cross-block communication through global memory within ONE
// kernel is NOT safe on MI355X (per-XCD L2 non-coherence, R14 failure).

// gfx9 DPP whole-wave shifts; bound_ctrl=1 -> out-of-range lanes read 0,
// exactly matching the conv's zero padding (W == wave width == 64).
constexpr int DPP_WAVE_SHL1 = 0x130;
constexpr int DPP_WAVE_SHR1 = 0x138;

// taps g(d)=exp(-d^2); center exactly 1.0. Loop: radius 2 (tap absmax
// 0.0078 — verified R7/R8). Checkpoint contraction: radius 3.
// Denominator +TINY dropped (R16): every colconv value is strictly
// positive at ~1e-4 scale, so 1e-10 is dead weight (numerator TINY kept,
// reference semantics).
constexpr float G1 = 0.36787944117144233f;
constexpr float G2 = 0.018315638888734179f;
constexpr float G3 = 1.2340980408667956e-4f;
// d^2 * g(d): center 0
constexpr float C1 = 0.36787944117144233f;
constexpr float C2 = 0.07326255555493671f;
constexpr float C3 = 1.110688236780116e-3f;

} // namespace

template <int CTRL>
__device__ __forceinline__ float dpp_shift(float v) {
  return __int_as_float(__builtin_amdgcn_update_dpp(
      0, __float_as_int(v), CTRL, 0xF, 0xF, true));
}

// explicit v_rcp_f32 + v_mul (1 ulp) — verified R12: __fdividef lowers to
// the full IEEE div sequence on ROCm; this was a 30% kernel-time cut.
__device__ __forceinline__ float fast_div(float n, float d) {
  return n * __builtin_amdgcn_rcpf(d);
}

__device__ __forceinline__ float block_reduce_sum(float v, float* red) {
#pragma unroll
  for (int off = 32; off; off >>= 1) v += __shfl_down(v, off, 64);
  const int wid = threadIdx.x >> 6;
  const int lane = threadIdx.x & 63;
  if (lane == 0) red[wid] = v;
  __syncthreads();
  if (threadIdx.x == 0) {
    float s = 0.f;
#pragma unroll
    for (int i = 0; i < NW; ++i) s += red[i];
    red[16] = s;
  }
  __syncthreads();
  return red[16];
}

__global__ __launch_bounds__(BLOCK, 2) void sinkhorn_kernel(
    const float* __restrict__ pred, const float* __restrict__ target,
    float* __restrict__ ws) {
  __shared__ float PA[PROWS * PW];
  __shared__ float PB[PROWS * PW];
  __shared__ float red[17];

  const int tid = threadIdx.x;
  const int wid = tid >> 6;
  const int lane = tid & 63;
  const int bc = blockIdx.x;

  const int cx = lane;          // owned column
  const int cy0 = wid * PX;     // owned row band [cy0, cy0+8)

  const float* Pp = pred + bc * N;
  const float* Qp = target + bc * N;

  // ---- zero the permanent halo rows (0,1,2 and 67,68,69) of both planes ----
  if (tid < 384) {
    int r = tid >> 6, c = tid & 63;
    int row = (r < 3) ? r : r + 64;
    PA[row * PW + c] = 0.f;
    PB[row * PW + c] = 0.f;
  }

  // ---- load + normalize (column layout) ----
  float ar[PX], br[PX], band[PX], eu[PX];
  float sa = 0.f, sb = 0.f;
#pragma unroll
  for (int k = 0; k < PX; ++k) {
    float va = Pp[(cy0 + k) * W + cx];
    float vb = Qp[(cy0 + k) * W + cx];
    ar[k] = va;
    br[k] = vb;
    sa += va;
    sb += vb;
  }
  sa = block_reduce_sum(sa, red);  // barriers also cover the halo-zero writes
  sb = block_reduce_sum(sb, red);
  const float isa = 1.0f / (sa + TINY);
  const float isb = 1.0f / (sb + TINY);
#pragma unroll
  for (int k = 0; k < PX; ++k) {
    ar[k] = ar[k] * isa + TINY;  // numerator of exp(u) = (a+TINY)/(S+TINY)
    br[k] = br[k] * isb + TINY;
    band[k] = 1.0f;              // EV = exp(v0) = 1
    eu[k] = 0.f;
  }

  // LDS addresses (hoisted). Plane row = logical row + 3.
  float* pa_w = &PA[(cy0 + 3) * PW + cx];
  float* pb_w = &PB[(cy0 + 3) * PW + cx];
  const float* pa_r = &PA[cy0 * PW + cx];
  const float* pb_r = &PB[cy0 * PW + cx];

  // radius-2 row conv of ONE row (along x, across lanes). R[k] depends only
  // on src[k], so boundary rows can be computed & written before interior.
  auto rowconv_k = [&](float bk) -> float {
    float p1 = dpp_shift<DPP_WAVE_SHL1>(bk);
    float m1 = dpp_shift<DPP_WAVE_SHR1>(bk);
    float p2 = dpp_shift<DPP_WAVE_SHL1>(p1);
    float m2 = dpp_shift<DPP_WAVE_SHR1>(m1);
    float s = fmaf(G1, m1 + p1, bk);  // center tap = 1.0
    return fmaf(G2, m2 + p2, s);
  };

  // radius-2 col conv + divide, interior-first (k=2..5 need no halo, so
  // they execute while the 4 halo ds_reads are in flight).
  auto col_update = [&](const float* P, const float (&R)[PX],
                        const float (&num)[PX], float (&dst)[PX]) {
    float h0 = P[1 * PW];    // logical cy0-2
    float h1 = P[2 * PW];    // logical cy0-1
    float h2 = P[11 * PW];   // logical cy0+8
    float h3 = P[12 * PW];   // logical cy0+9
#pragma unroll
    for (int k = 2; k < 6; ++k) {
      float s = fmaf(G1, R[k - 1] + R[k + 1], R[k]);
      s = fmaf(G2, R[k - 2] + R[k + 2], s);
      dst[k] = fast_div(num[k], s);
    }
    {
      float s = fmaf(G1, h1 + R[1], R[0]);
      s = fmaf(G2, h0 + R[2], s);
      dst[0] = fast_div(num[0], s);
    }
    {
      float s = fmaf(G1, R[0] + R[2], R[1]);
      s = fmaf(G2, h1 + R[3], s);
      dst[1] = fast_div(num[1], s);
    }
    {
      float s = fmaf(G1, R[5] + R[7], R[6]);
      s = fmaf(G2, R[4] + h2, s);
      dst[6] = fast_div(num[6], s);
    }
    {
      float s = fmaf(G1, R[6] + h2, R[7]);
      s = fmaf(G2, R[5] + h3, s);
      dst[7] = fast_div(num[7], s);
    }
  };

  // one Sinkhorn half-step: dst = num / (K (*) src); 1 barrier.
  // Boundary rows first + early ds_write -> write latency drains under
  // the interior rowconv, shrinking the pre-barrier lgkmcnt(0) wait.
  auto half_iter = [&](float* Pw, const float* Pr, const float (&num)[PX],
                       const float (&src)[PX], float (&dst)[PX]) {
    float R[PX];
    R[0] = rowconv_k(src[0]);
    R[1] = rowconv_k(src[1]);
    R[6] = rowconv_k(src[6]);
    R[7] = rowconv_k(src[7]);
    Pw[0 * PW] = R[0];
    Pw[1 * PW] = R[1];
    Pw[6 * PW] = R[6];
    Pw[7 * PW] = R[7];
    R[2] = rowconv_k(src[2]);
    R[3] = rowconv_k(src[3]);
    R[4] = rowconv_k(src[4]);
    R[5] = rowconv_k(src[5]);
    __syncthreads();
    col_update(Pr, R, num, dst);
  };

  // EMD contraction at a checkpoint (radius 3). Opening barrier: we write
  // BOTH planes, so wait for all waves' preceding col_update reads (the
  // steady loop is safe only because A/B phases touch disjoint planes).
  auto contraction = [&]() -> float {
    __syncthreads();
    float R1[PX], R2[PX];
    {
      float p1[PX], m1[PX], p2[PX], m2[PX], p3[PX], m3[PX];
#pragma unroll
      for (int k = 0; k < PX; ++k) {
        p1[k] = dpp_shift<DPP_WAVE_SHL1>(band[k]);
        m1[k] = dpp_shift<DPP_WAVE_SHR1>(band[k]);
      }
#pragma unroll
      for (int k = 0; k < PX; ++k) {
        p2[k] = dpp_shift<DPP_WAVE_SHL1>(p1[k]);
        m2[k] = dpp_shift<DPP_WAVE_SHR1>(m1[k]);
      }
#pragma unroll
      for (int k = 0; k < PX; ++k) {
        p3[k] = dpp_shift<DPP_WAVE_SHL1>(p2[k]);
        m3[k] = dpp_shift<DPP_WAVE_SHR1>(m2[k]);
      }
#pragma unroll
      for (int k = 0; k < PX; ++k) {
        float a1 = m1[k] + p1[k], a2 = m2[k] + p2[k], a3 = m3[k] + p3[k];
        float s1 = fmaf(G1, a1, band[k]);
        s1 = fmaf(G2, a2, s1);
        R1[k] = fmaf(G3, a3, s1);
        float s2 = C1 * a1;
        s2 = fmaf(C2, a2, s2);
        R2[k] = fmaf(C3, a3, s2);
      }
    }
    // boundary rows for radius-3 neighbors: 0,1,2 and 5,6,7
    pa_w[0 * PW] = R1[0];  pb_w[0 * PW] = R2[0];
    pa_w[1 * PW] = R1[1];  pb_w[1 * PW] = R2[1];
    pa_w[2 * PW] = R1[2];  pb_w[2 * PW] = R2[2];
    pa_w[5 * PW] = R1[5];  pb_w[5 * PW] = R2[5];
    pa_w[6 * PW] = R1[6];  pb_w[6 * PW] = R2[6];
    pa_w[7 * PW] = R1[7];  pb_w[7 * PW] = R2[7];
    __syncthreads();
    float local = 0.f;
    float w1[PX + 6], w2[PX + 6];
    w1[0] = pa_r[0 * PW];   w2[0] = pb_r[0 * PW];
    w1[1] = pa_r[1 * PW];   w2[1] = pb_r[1 * PW];
    w1[2] = pa_r[2 * PW];   w2[2] = pb_r[2 * PW];
#pragma unroll
    for (int k = 0; k < PX; ++k) {
      w1[3 + k] = R1[k];
      w2[3 + k] = R2[k];
    }
    w1[11] = pa_r[11 * PW]; w2[11] = pb_r[11 * PW];
    w1[12] = pa_r[12 * PW]; w2[12] = pb_r[12 * PW];
    w1[13] = pa_r[13 * PW]; w2[13] = pb_r[13 * PW];
#pragma unroll
    for (int k = 0; k < PX; ++k) {
      float s = C1 * (w1[k + 2] + w1[k + 4]);        // GC on G-plane (center 0)
      s = fmaf(C2, w1[k + 1] + w1[k + 5], s);
      s = fmaf(C3, w1[k + 0] + w1[k + 6], s);
      s += w2[k + 3];                                 // G on GC-plane, center 1
      s = fmaf(G1, w2[k + 2] + w2[k + 4], s);
      s = fmaf(G2, w2[k + 1] + w2[k + 5], s);
      s = fmaf(G3, w2[k + 0] + w2[k + 6], s);
      local = fmaf(eu[k], s, local);
    }
    return block_reduce_sum(local, red);  // internal barriers fence reads
  };

  // one checkpointed segment: LEN full iterations + 1 checkpoint iteration.
  // Compile-time LEN -> full unroll (R9/R12 evidence: unrolled is faster).
  auto run_seg = [&](auto len_c) -> float {
    constexpr int LEN = decltype(len_c)::value;
#pragma unroll
    for (int it = 0; it < LEN; ++it) {
      half_iter(pa_w, pa_r, ar, band, band);  // band := exp(u)
      half_iter(pb_w, pb_r, br, band, band);  // band := exp(v)
    }
    half_iter(pa_w, pa_r, ar, band, eu);      // checkpoint exp(u), kept
    half_iter(pb_w, pb_r, br, eu, band);      // checkpoint exp(v)
    return contraction();
  };

  // ---- 32 iterations, checkpoints after 12/22/32 (spacing 10) ----
  float e0 = run_seg(std::integral_constant<int, 11>{});
  float e1 = run_seg(std::integral_constant<int, 9>{});
  float e2 = run_seg(std::integral_constant<int, 9>{});

  // ---- per-channel Aitken extrapolation; publish via kernel boundary ----
  if (tid == 0) {
    float d1 = e1 - e0, d2 = e2 - e1;
    float est = e2;
    float r = d2 / d1;                 // = q^10 (NaN/inf -> guards false)
    if (r > 0.001f && r < 0.97f) {
      float corr = d2 * r / (1.0f - r);
      corr = fminf(0.06f, fmaxf(-0.06f, corr));
      est = e2 + corr;
    }
    ws[bc] = est;
  }
}

__global__ void mean_kernel(const float* __restrict__ ws,
                            float* __restrict__ out) {
  int t = threadIdx.x;
  float v = (t < BC) ? ws[t] : 0.f;
#pragma unroll
  for (int off = 32; off; off >>= 1) v += __shfl_down(v, off, 64);
  if (t == 0) out[0] = v * (1.0f / BC);
}

extern "C" void kernel_launch(void* const* d_in, const int* in_sizes, int n_in,
                              void* d_out, int out_size, void* d_ws,
                              size_t ws_size, hipStream_t stream) {
  const float* pred = (const float*)d_in[0];
  const float* target = (const float*)d_in[1];
  float* out = (float*)d_out;
  float* ws = (float*)d_ws;

  sinkhorn_kernel<<<BC, BLOCK, 0, stream>>>(pred, target, ws);
  mean_kernel<<<1, 64, 0, stream>>>(ws, out);
}